// Round 5
// baseline (907.653 us; speedup 1.0000x reference)
//
#include <hip/hip_runtime.h>
#include <hip/hip_bf16.h>
#include <cstdint>

constexpr int B_    = 4;
constexpr int NIN_  = 50000;
constexpr int NOUT_ = 50000;
constexpr int E_    = 819200;
constexpr int CI    = 16;
constexpr int CO    = 16;
constexpr int Hh    = 100;

constexpr int M      = 32;            // edges per wave-tile
constexpr int NBLK   = 256;           // persistent blocks (1 per CU)
constexpr int NTILES = E_ / M;        // 25600
constexpr int BITER  = NTILES / 8;    // 3200 block-iterations (8 waves each)
constexpr size_t LDS_BYTES = 163840;  // 128 KB weights + 8 waves x 4 KB xs

typedef __attribute__((ext_vector_type(8))) short bf16x8;
typedef __attribute__((ext_vector_type(4))) float f32x4;

union frag { bf16x8 v; unsigned u[4]; };

__device__ inline unsigned pk2(float a, float b) {
    // v_cvt_pk_bf16_f32: u32 = [bf16(a) lo | bf16(b) hi]
    unsigned r;
    asm("v_cvt_pk_bf16_f32 %0, %1, %2" : "=v"(r) : "v"(a), "v"(b));
    return r;
}

// 16B-chunk XOR bank swizzle within a 128-bf16 row (verified rounds 2-4)
__device__ inline int chunkXor(int r) { return ((r & 7) << 3) ^ ((r & 8) << 1); }
__device__ inline int swz(int r, int k) { return r * 128 + (k ^ chunkXor(r)); }

// sigma-wiring: out-wire placed at D(nt,kg,q) is consumed at k_eff = sigma(m).
// sigma(m): nt=m>>4, kg=(m>>2)&3, q=m&3 -> (nt&3)*32 + kg*8 + (nt>>2)*4 + q
// inverse used in prep below.

// ---------------- prep: swizzled+sigma'd bf16 weight image ------------------
__global__ __launch_bounds__(256)
void prep_kernel(const float* __restrict__ w1, const float* __restrict__ w2,
                 const float* __restrict__ w3, const float* __restrict__ w4,
                 const float* __restrict__ b1, const float* __restrict__ b2,
                 const float* __restrict__ b3, const float* __restrict__ b4,
                 unsigned short* __restrict__ wcat, unsigned short* __restrict__ W1T,
                 float* __restrict__ b1p, float* __restrict__ b2p,
                 float* __restrict__ b3p, float* __restrict__ b4p)
{
    const int i = blockIdx.x * 256 + threadIdx.x;
    auto bf = [](float f) {
        __hip_bfloat16 h = __float2bfloat16(f);
        return *reinterpret_cast<unsigned short*>(&h);
    };
    auto inv = [](int kpos) {   // sigma^-1
        return ((kpos >> 2) & 1) * 64 + ((kpos >> 5) & 3) * 16 +
               ((kpos >> 3) & 3) * 4 + (kpos & 3);
    };
    if (i < 32768) {                     // W2 [0,16384), W3 [16384,32768): rows 128 x k 128
        int j = i & 16383; int r = j >> 7, kz = j & 127;
        int kpos = kz ^ chunkXor(r);
        int u = inv(kpos);               // source in-wire
        const float* w = (i < 16384) ? w2 : w3;
        wcat[i] = (r < Hh && u < Hh) ? bf(w[u * Hh + r]) : (unsigned short)0;
    } else if (i < 65536) {              // W4: rows 256 x k 128
        int j = i - 32768; int r = j >> 7, kz = j & 127;
        int kpos = kz ^ chunkXor(r);
        int u = inv(kpos);
        wcat[i] = (u < Hh) ? bf(w4[u * 256 + r]) : (unsigned short)0;
    } else if (i < 69632) {              // W1T [wire:128][k:32], k = attr idx (no sigma)
        int j = i - 65536; int wi = j >> 5, k = j & 31;
        W1T[j] = (k < 6 && wi < Hh) ? bf(w1[k * Hh + wi]) : (unsigned short)0;
    } else if (i < 69760) { int j = i - 69632; b1p[j] = (j < Hh) ? b1[j] : 0.f; }
    else if (i < 69888) { int j = i - 69760; b2p[j] = (j < Hh) ? b2[j] : 0.f; }
    else if (i < 70016) { int j = i - 69888; b3p[j] = (j < Hh) ? b3[j] : 0.f; }
    else if (i < 70272) { int j = i - 70016; b4p[j] = b4[j]; }
}

// ---- hidden layer: out = relu(W @ in + b) entirely in registers -----------
// A = W (rows = out-wires) from LDS; B = h (cols = edges) in regs; D packs
// straight into next layer's B-frags via sigma-wiring (no cross-lane moves).
__device__ inline void hidden_layer(const unsigned short* __restrict__ Wl,
                                    const float* __restrict__ bp,
                                    const frag (&in)[2][4], frag (&out)[2][4],
                                    int cl, int kg)
{
    #pragma unroll
    for (int nt = 0; nt < 8; ++nt) {
        bf16x8 wf[4];
        #pragma unroll
        for (int ks = 0; ks < 4; ++ks)
            wf[ks] = *reinterpret_cast<const bf16x8*>(
                Wl + swz(nt * 16 + cl, ks * 32 + kg * 8));
        f32x4 bias = *reinterpret_cast<const f32x4*>(bp + nt * 16 + kg * 4);
        #pragma unroll
        for (int et = 0; et < 2; ++et) {
            f32x4 acc = bias;
            #pragma unroll
            for (int ks = 0; ks < 4; ++ks)
                acc = __builtin_amdgcn_mfma_f32_16x16x32_bf16(wf[ks], in[et][ks].v, acc, 0, 0, 0);
            out[et][nt & 3].u[((nt >> 2) << 1) + 0] = pk2(fmaxf(acc[0], 0.f), fmaxf(acc[1], 0.f));
            out[et][nt & 3].u[((nt >> 2) << 1) + 1] = pk2(fmaxf(acc[2], 0.f), fmaxf(acc[3], 0.f));
        }
    }
}

// ---------------- main kernel: persistent blocks, LDS-resident weights -----
__global__ __launch_bounds__(512, 2)
void edge_kernel(const float* __restrict__ x, const float* __restrict__ ipos,
                 const float* __restrict__ opos, const int* __restrict__ esrc,
                 const int* __restrict__ edst,
                 const unsigned short* __restrict__ wcat,
                 const unsigned short* __restrict__ W1T,
                 const float* __restrict__ b1p, const float* __restrict__ b2p,
                 const float* __restrict__ b3p, const float* __restrict__ b4p,
                 float* __restrict__ agg, float* __restrict__ deg)
{
    extern __shared__ char lds[];
    unsigned short* Wlds = (unsigned short*)lds;   // bf16 idx: W2 @0, W3 @16384, W4 @32768

    const int tid  = threadIdx.x;
    const int wv   = __builtin_amdgcn_readfirstlane(tid >> 6);
    const int lane = tid & 63;
    const int cl   = lane & 15;
    const int kg   = lane >> 4;

    // stage 128 KB weight image linearly (once per block)
    {
        const float4* s4 = (const float4*)wcat;
        float4* d4 = (float4*)lds;
        for (int i = tid; i < 8192; i += 512) d4[i] = s4[i];
    }
    // persistent W1 A-frags (8 x 16B)
    bf16x8 a1w[8];
    #pragma unroll
    for (int nt = 0; nt < 8; ++nt)
        a1w[nt] = *reinterpret_cast<const bf16x8*>(W1T + (nt * 16 + cl) * 32 + kg * 8);
    __syncthreads();   // the only barrier

    uint2* xs = (uint2*)(lds + 131072 + wv * 4096);   // wave-private [i:16][e:32] bf16x4

    for (int bt = blockIdx.x; bt < BITER; bt += NBLK) {
        const int e0 = (bt * 8 + wv) * M;
        const int eA = e0 + (lane & 31);
        const int srcv = esrc[eA];
        if (lane < 32) atomicAdd(&deg[edst[eA]], 1.0f);
        const int d0 = edst[e0 + cl];
        const int d1 = edst[e0 + 16 + cl];

        // ---- B1 attr frags (k=0..5 live in kg==0 lanes) ----
        frag b1f[2];
        #pragma unroll
        for (int et = 0; et < 2; ++et) {
            frag f; f.u[0] = f.u[1] = f.u[2] = f.u[3] = 0u;
            if (kg == 0) {
                const int e = e0 + cl + 16 * et;
                const int s = esrc[e], d = edst[e];
                f.u[0] = pk2(opos[d * 3 + 0], opos[d * 3 + 1]);
                f.u[1] = pk2(opos[d * 3 + 2], ipos[s * 3 + 0]);
                f.u[2] = pk2(ipos[s * 3 + 1], ipos[s * 3 + 2]);
            }
            b1f[et] = f;
        }

        // ---- layer 1 (K=32, W1 frags persistent in regs) ----
        frag B2[2][4];
        #pragma unroll
        for (int nt = 0; nt < 8; ++nt) {
            f32x4 bias = *reinterpret_cast<const f32x4*>(b1p + nt * 16 + kg * 4);
            #pragma unroll
            for (int et = 0; et < 2; ++et) {
                f32x4 acc = bias;
                acc = __builtin_amdgcn_mfma_f32_16x16x32_bf16(a1w[nt], b1f[et].v, acc, 0, 0, 0);
                B2[et][nt & 3].u[((nt >> 2) << 1) + 0] = pk2(fmaxf(acc[0], 0.f), fmaxf(acc[1], 0.f));
                B2[et][nt & 3].u[((nt >> 2) << 1) + 1] = pk2(fmaxf(acc[2], 0.f), fmaxf(acc[3], 0.f));
            }
        }

        // ---- x gather issue early (consumed after layer 2) ----
        float4 xg[4][2];
        {
            const int ih = lane >> 5;
            const float* xp0 = x + (size_t)srcv * CI + ih * 8;
            #pragma unroll
            for (int b = 0; b < 4; ++b) {
                const float* xp = xp0 + (size_t)b * (NIN_ * CI);
                xg[b][0] = *reinterpret_cast<const float4*>(xp);
                xg[b][1] = *reinterpret_cast<const float4*>(xp + 4);
            }
        }

        // ---- layer 2 ----
        frag B3[2][4];
        hidden_layer(Wlds, b2p, B2, B3, cl, kg);

        // ---- xs write: [i][e] 4xbf16 over b (wave-private) ----
        {
            const int ih = lane >> 5;
            const int e  = lane & 31;
            #pragma unroll
            for (int i2 = 0; i2 < 2; ++i2)
                #pragma unroll
                for (int r = 0; r < 4; ++r) {
                    uint2 v;
                    v.x = pk2(xg[0][i2][r], xg[1][i2][r]);
                    v.y = pk2(xg[2][i2][r], xg[3][i2][r]);
                    xs[(ih * 8 + i2 * 4 + r) * 32 + e] = v;
                }
        }

        // ---- layer 3 ----
        frag B4[2][4];
        hidden_layer(Wlds + 16384, b3p, B3, B4, cl, kg);

        // ---- layer 4 + fused message ----
        float macc[2][16];
        #pragma unroll
        for (int et = 0; et < 2; ++et)
            #pragma unroll
            for (int q = 0; q < 16; ++q) macc[et][q] = 0.f;

        const unsigned short* W4l = Wlds + 32768;
        #pragma unroll
        for (int nt = 0; nt < 16; ++nt) {
            bf16x8 wf[4];
            #pragma unroll
            for (int ks = 0; ks < 4; ++ks)
                wf[ks] = *reinterpret_cast<const bf16x8*>(
                    W4l + swz(nt * 16 + cl, ks * 32 + kg * 8));
            f32x4 bias = *reinterpret_cast<const f32x4*>(b4p + nt * 16 + kg * 4);
            const uint2 xp0 = xs[nt * 32 + cl];
            const uint2 xp1 = xs[nt * 32 + 16 + cl];
            #pragma unroll
            for (int et = 0; et < 2; ++et) {
                f32x4 acc = bias;
                #pragma unroll
                for (int ks = 0; ks < 4; ++ks)
                    acc = __builtin_amdgcn_mfma_f32_16x16x32_bf16(wf[ks], B4[et][ks].v, acc, 0, 0, 0);
                const uint2 xp = et ? xp1 : xp0;
                const float xb0 = __uint_as_float(xp.x << 16);
                const float xb1 = __uint_as_float(xp.x & 0xffff0000u);
                const float xb2 = __uint_as_float(xp.y << 16);
                const float xb3 = __uint_as_float(xp.y & 0xffff0000u);
                #pragma unroll
                for (int j = 0; j < 4; ++j) {
                    macc[et][0 * 4 + j] = fmaf(xb0, acc[j], macc[et][0 * 4 + j]);
                    macc[et][1 * 4 + j] = fmaf(xb1, acc[j], macc[et][1 * 4 + j]);
                    macc[et][2 * 4 + j] = fmaf(xb2, acc[j], macc[et][2 * 4 + j]);
                    macc[et][3 * 4 + j] = fmaf(xb3, acc[j], macc[et][3 * 4 + j]);
                }
            }
        }

        // ---- scatter: lane holds (edge cl|16et, o = kg*4+j, all b) ----
        #pragma unroll
        for (int et = 0; et < 2; ++et) {
            const int d = et ? d1 : d0;
            float* p = agg + (size_t)d * (B_ * CO) + kg * 4;
            #pragma unroll
            for (int b = 0; b < 4; ++b)
                #pragma unroll
                for (int j = 0; j < 4; ++j)
                    atomicAdd(p + b * 16 + j, macc[et][b * 4 + j]);
        }
    }
}

// out[b][n][o] = agg[n][b][o] / max(deg[n],1) + bias[o]
__global__ __launch_bounds__(256)
void finalize_kernel(const float* __restrict__ agg, const float* __restrict__ deg,
                     const float* __restrict__ bias, float* __restrict__ out)
{
    const int idx = blockIdx.x * 256 + threadIdx.x;
    if (idx >= B_ * NOUT_ * CO) return;
    const int o = idx & 15;
    const int n = (idx >> 4) % NOUT_;
    const int b = idx / (NOUT_ * CO);
    const float d = fmaxf(deg[n], 1.0f);
    out[idx] = agg[(size_t)n * (B_ * CO) + b * CO + o] / d + bias[o];
}

extern "C" void kernel_launch(void* const* d_in, const int* in_sizes, int n_in,
                              void* d_out, int out_size, void* d_ws, size_t ws_size,
                              hipStream_t stream)
{
    const float* x    = (const float*)d_in[0];
    const float* ipos = (const float*)d_in[1];
    const float* opos = (const float*)d_in[2];
    const int*   esrc = (const int*)d_in[3];
    const int*   edst = (const int*)d_in[4];
    const float* w1   = (const float*)d_in[5];
    const float* b1   = (const float*)d_in[6];
    const float* w2   = (const float*)d_in[7];
    const float* b2   = (const float*)d_in[8];
    const float* w3   = (const float*)d_in[9];
    const float* b3   = (const float*)d_in[10];
    const float* w4   = (const float*)d_in[11];
    const float* b4   = (const float*)d_in[12];
    const float* bias = (const float*)d_in[14];

    // Weight scratch in d_out's head (~139 KB); finalize overwrites it.
    char* ob = (char*)d_out;
    unsigned short* wcat = (unsigned short*)ob;              // 131072 B LDS image
    unsigned short* W1T  = (unsigned short*)(ob + 131072);   // 8192 B
    float* b1p = (float*)(ob + 139264);
    float* b2p = (float*)(ob + 139776);
    float* b3p = (float*)(ob + 140288);
    float* b4p = (float*)(ob + 140800);                      // ends 141824 B

    float* agg = (float*)d_ws;
    float* deg = agg + (size_t)NOUT_ * (B_ * CO);

    hipMemsetAsync(d_ws, 0,
                   ((size_t)NOUT_ * (B_ * CO) + NOUT_) * sizeof(float), stream);

    prep_kernel<<<275, 256, 0, stream>>>(w1, w2, w3, w4, b1, b2, b3, b4,
                                         wcat, W1T, b1p, b2p, b3p, b4p);

    hipFuncSetAttribute(reinterpret_cast<const void*>(edge_kernel),
                        hipFuncAttributeMaxDynamicSharedMemorySize,
                        (int)LDS_BYTES);
    edge_kernel<<<NBLK, 512, LDS_BYTES, stream>>>(
        x, ipos, opos, esrc, edst, wcat, W1T, b1p, b2p, b3p, b4p, agg, deg);

    const int total = B_ * NOUT_ * CO;
    finalize_kernel<<<(total + 255) / 256, 256, 0, stream>>>(agg, deg, bias,
                                                             (float*)d_out);
}

// Round 7
// 359.736 us; speedup vs baseline: 2.5231x; 2.5231x over previous
//
#include <hip/hip_runtime.h>
#include <hip/hip_bf16.h>
#include <cstdint>

constexpr int B_    = 4;
constexpr int NIN_  = 50000;
constexpr int NOUT_ = 50000;
constexpr int E_    = 819200;
constexpr int CI    = 16;
constexpr int CO    = 16;
constexpr int Hh    = 100;

constexpr int M      = 32;            // edges per wave-tile
constexpr int NBLK   = 256;           // persistent blocks (1 per CU)
constexpr int NTILES = E_ / M;        // 25600
constexpr int BITER  = NTILES / 8;    // 3200 block-iterations (8 waves each)
constexpr size_t LDS_BYTES = 163840;  // 128 KB weights + 8 waves x 4 KB xs

typedef __attribute__((ext_vector_type(8))) short bf16x8;
typedef __attribute__((ext_vector_type(4))) float f32x4;

union frag { bf16x8 v; unsigned u[4]; };

__device__ inline unsigned pk2(float a, float b) {
    // v_cvt_pk_bf16_f32: u32 = [bf16(a) lo | bf16(b) hi]
    unsigned r;
    asm("v_cvt_pk_bf16_f32 %0, %1, %2" : "=v"(r) : "v"(a), "v"(b));
    return r;
}

// 16B-chunk XOR bank swizzle within a 128-bf16 row (verified rounds 2-5)
__device__ inline int chunkXor(int r) { return ((r & 7) << 3) ^ ((r & 8) << 1); }
__device__ inline int swz(int r, int k) { return r * 128 + (k ^ chunkXor(r)); }

// sigma-wiring: out-wire at D(nt,kg,q) is consumed at k_eff = sigma(m) =
// (nt&3)*32 + kg*8 + (nt>>2)*4 + q ; prep bakes sigma^-1 into the weight image.

// ---------------- prep: swizzled+sigma'd bf16 weight image ------------------
__global__ __launch_bounds__(256)
void prep_kernel(const float* __restrict__ w1, const float* __restrict__ w2,
                 const float* __restrict__ w3, const float* __restrict__ w4,
                 const float* __restrict__ b1, const float* __restrict__ b2,
                 const float* __restrict__ b3, const float* __restrict__ b4,
                 unsigned short* __restrict__ wcat, unsigned short* __restrict__ W1T,
                 float* __restrict__ b1p, float* __restrict__ b2p,
                 float* __restrict__ b3p, float* __restrict__ b4p)
{
    const int i = blockIdx.x * 256 + threadIdx.x;
    auto bf = [](float f) {
        __hip_bfloat16 h = __float2bfloat16(f);
        return *reinterpret_cast<unsigned short*>(&h);
    };
    auto inv = [](int kpos) {   // sigma^-1
        return ((kpos >> 2) & 1) * 64 + ((kpos >> 5) & 3) * 16 +
               ((kpos >> 3) & 3) * 4 + (kpos & 3);
    };
    if (i < 32768) {                     // W2 [0,16384), W3 [16384,32768)
        int j = i & 16383; int r = j >> 7, kz = j & 127;
        int kpos = kz ^ chunkXor(r);
        int u = inv(kpos);
        const float* w = (i < 16384) ? w2 : w3;
        wcat[i] = (r < Hh && u < Hh) ? bf(w[u * Hh + r]) : (unsigned short)0;
    } else if (i < 65536) {              // W4: rows 256 x k 128
        int j = i - 32768; int r = j >> 7, kz = j & 127;
        int kpos = kz ^ chunkXor(r);
        int u = inv(kpos);
        wcat[i] = (u < Hh) ? bf(w4[u * 256 + r]) : (unsigned short)0;
    } else if (i < 69632) {              // W1T [wire:128][k:32]
        int j = i - 65536; int wi = j >> 5, k = j & 31;
        W1T[j] = (k < 6 && wi < Hh) ? bf(w1[k * Hh + wi]) : (unsigned short)0;
    } else if (i < 69760) { int j = i - 69632; b1p[j] = (j < Hh) ? b1[j] : 0.f; }
    else if (i < 69888) { int j = i - 69760; b2p[j] = (j < Hh) ? b2[j] : 0.f; }
    else if (i < 70016) { int j = i - 69888; b3p[j] = (j < Hh) ? b3[j] : 0.f; }
    else if (i < 70272) { int j = i - 70016; b4p[j] = b4[j]; }
}

// ---- hidden layer: out = relu(W @ in + b) entirely in registers -----------
__device__ inline void hidden_layer(const unsigned short* __restrict__ Wl,
                                    const float* __restrict__ bp,
                                    const frag (&in)[2][4], frag (&out)[2][4],
                                    int cl, int kg)
{
    #pragma unroll
    for (int nt = 0; nt < 8; ++nt) {
        bf16x8 wf[4];
        #pragma unroll
        for (int ks = 0; ks < 4; ++ks)
            wf[ks] = *reinterpret_cast<const bf16x8*>(
                Wl + swz(nt * 16 + cl, ks * 32 + kg * 8));
        f32x4 bias = *reinterpret_cast<const f32x4*>(bp + nt * 16 + kg * 4);
        #pragma unroll
        for (int et = 0; et < 2; ++et) {
            f32x4 acc = bias;
            #pragma unroll
            for (int ks = 0; ks < 4; ++ks)
                acc = __builtin_amdgcn_mfma_f32_16x16x32_bf16(wf[ks], in[et][ks].v, acc, 0, 0, 0);
            out[et][nt & 3].u[((nt >> 2) << 1) + 0] = pk2(fmaxf(acc[0], 0.f), fmaxf(acc[1], 0.f));
            out[et][nt & 3].u[((nt >> 2) << 1) + 1] = pk2(fmaxf(acc[2], 0.f), fmaxf(acc[3], 0.f));
        }
    }
}

// ---------------- main kernel: persistent blocks, LDS-resident weights -----
__global__ __launch_bounds__(512, 2)
void edge_kernel(const float* __restrict__ x, const float* __restrict__ ipos,
                 const float* __restrict__ opos, const int* __restrict__ esrc,
                 const int* __restrict__ edst,
                 const unsigned short* __restrict__ wcat,
                 const unsigned short* __restrict__ W1T,
                 const float* __restrict__ b1p, const float* __restrict__ b2p,
                 const float* __restrict__ b3p, const float* __restrict__ b4p,
                 float* __restrict__ agg, float* __restrict__ deg)
{
    extern __shared__ char lds[];
    unsigned short* Wlds = (unsigned short*)lds;   // W2 @0, W3 @16384, W4 @32768

    const int tid  = threadIdx.x;
    const int wv   = __builtin_amdgcn_readfirstlane(tid >> 6);
    const int lane = tid & 63;
    const int cl   = lane & 15;
    const int kg   = lane >> 4;

    // ---- prologue: first tile metadata (overlaps weight staging) ----
    int srcv, dstv; unsigned au0, au1, au2;
    {
        const int e0 = (blockIdx.x * 8 + wv) * M;
        const int eA = e0 + (lane & 31);
        srcv = esrc[eA]; dstv = edst[eA];
        if (lane < 32) atomicAdd(&deg[dstv], 1.0f);
        float o0 = opos[dstv * 3 + 0], o1 = opos[dstv * 3 + 1], o2 = opos[dstv * 3 + 2];
        float i0 = ipos[srcv * 3 + 0], i1 = ipos[srcv * 3 + 1], i2 = ipos[srcv * 3 + 2];
        au0 = pk2(o0, o1); au1 = pk2(o2, i0); au2 = pk2(i1, i2);
    }

    // stage 128 KB weight image (once per block)
    {
        const float4* s4 = (const float4*)wcat;
        float4* d4 = (float4*)lds;
        for (int i = tid; i < 8192; i += 512) d4[i] = s4[i];
    }
    // persistent W1 A-frags
    bf16x8 a1w[8];
    #pragma unroll
    for (int nt = 0; nt < 8; ++nt)
        a1w[nt] = *reinterpret_cast<const bf16x8*>(W1T + (nt * 16 + cl) * 32 + kg * 8);
    __syncthreads();   // the only barrier

    uint2* xs = (uint2*)(lds + 131072 + wv * 4096);   // wave-private [i:16][e:32]

    for (int bt = blockIdx.x; bt < BITER; bt += NBLK) {
        // ---- x gather: issue first (consumed after layer 2) ----
        float4 xg[4][2];
        {
            const int ih = lane >> 5;
            const float* xp0 = x + (size_t)srcv * CI + ih * 8;
            #pragma unroll
            for (int b = 0; b < 4; ++b) {
                const float* xp = xp0 + (size_t)b * (NIN_ * CI);
                xg[b][0] = *reinterpret_cast<const float4*>(xp);
                xg[b][1] = *reinterpret_cast<const float4*>(xp + 4);
            }
        }

        // ---- B1 attr frags from packed regs via shfl (no divergence) ----
        frag b1f[2];
        #pragma unroll
        for (int et = 0; et < 2; ++et) {
            const int sl = et * 16 + cl;
            unsigned s0 = __shfl(au0, sl), s1 = __shfl(au1, sl), s2 = __shfl(au2, sl);
            frag f;
            f.u[0] = (kg == 0) ? s0 : 0u;
            f.u[1] = (kg == 0) ? s1 : 0u;
            f.u[2] = (kg == 0) ? s2 : 0u;
            f.u[3] = 0u;
            b1f[et] = f;
        }

        // ---- layer 1 (K=32, W1 frags persistent) ----
        frag B2[2][4];
        #pragma unroll
        for (int nt = 0; nt < 8; ++nt) {
            f32x4 bias = *reinterpret_cast<const f32x4*>(b1p + nt * 16 + kg * 4);
            #pragma unroll
            for (int et = 0; et < 2; ++et) {
                f32x4 acc = bias;
                acc = __builtin_amdgcn_mfma_f32_16x16x32_bf16(a1w[nt], b1f[et].v, acc, 0, 0, 0);
                B2[et][nt & 3].u[((nt >> 2) << 1) + 0] = pk2(fmaxf(acc[0], 0.f), fmaxf(acc[1], 0.f));
                B2[et][nt & 3].u[((nt >> 2) << 1) + 1] = pk2(fmaxf(acc[2], 0.f), fmaxf(acc[3], 0.f));
            }
        }

        // ---- prefetch next tile metadata (hidden under layers 2-4) ----
        int nsrc = srcv, ndst = dstv;
        unsigned na0 = au0, na1 = au1, na2 = au2;
        {
            const int nbt = bt + NBLK;
            if (nbt < BITER) {
                const int ne0 = (nbt * 8 + wv) * M;
                const int neA = ne0 + (lane & 31);
                nsrc = esrc[neA]; ndst = edst[neA];
                if (lane < 32) atomicAdd(&deg[ndst], 1.0f);
                float o0 = opos[ndst * 3 + 0], o1 = opos[ndst * 3 + 1], o2 = opos[ndst * 3 + 2];
                float i0 = ipos[nsrc * 3 + 0], i1 = ipos[nsrc * 3 + 1], i2 = ipos[nsrc * 3 + 2];
                na0 = pk2(o0, o1); na1 = pk2(o2, i0); na2 = pk2(i1, i2);
            }
        }

        // ---- layer 2 ----
        frag B3[2][4];
        hidden_layer(Wlds, b2p, B2, B3, cl, kg);

        // ---- xs write: [i][e] packed bf16 over b (wave-private) ----
        {
            const int ih = lane >> 5;
            const int e  = lane & 31;
            #pragma unroll
            for (int i2 = 0; i2 < 2; ++i2)
                #pragma unroll
                for (int r = 0; r < 4; ++r) {
                    uint2 v;
                    v.x = pk2(xg[0][i2][r], xg[1][i2][r]);
                    v.y = pk2(xg[2][i2][r], xg[3][i2][r]);
                    xs[(ih * 8 + i2 * 4 + r) * 32 + e] = v;
                }
        }

        // ---- layer 3 ----
        frag B4[2][4];
        hidden_layer(Wlds + 16384, b3p, B3, B4, cl, kg);

        // ---- layer 4 + fused message (A=h, B=W4 -> D row=edge, col=o) ----
        float macc[2][16];   // [et][b*4 + j], j = edge kg*4+j
        #pragma unroll
        for (int et = 0; et < 2; ++et)
            #pragma unroll
            for (int q = 0; q < 16; ++q) macc[et][q] = 0.f;

        const unsigned short* W4l = Wlds + 32768;
        #pragma unroll
        for (int nt = 0; nt < 16; ++nt) {
            bf16x8 wf[4];
            #pragma unroll
            for (int ks = 0; ks < 4; ++ks)
                wf[ks] = *reinterpret_cast<const bf16x8*>(
                    W4l + swz(nt * 16 + cl, ks * 32 + kg * 8));
            const float bv = b4p[nt * 16 + cl];     // bias per col (o = cl)
            #pragma unroll
            for (int et = 0; et < 2; ++et) {
                // x for edges kg*4 + {0..3}, i = nt: 4 consecutive uint2
                const uint4 xa = *reinterpret_cast<const uint4*>(
                    &xs[nt * 32 + et * 16 + kg * 4]);      // j=0,1
                const uint4 xb = *reinterpret_cast<const uint4*>(
                    &xs[nt * 32 + et * 16 + kg * 4 + 2]);  // j=2,3
                f32x4 acc = {bv, bv, bv, bv};
                #pragma unroll
                for (int ks = 0; ks < 4; ++ks)
                    acc = __builtin_amdgcn_mfma_f32_16x16x32_bf16(B4[et][ks].v, wf[ks], acc, 0, 0, 0);
                const unsigned w01[4] = {xa.x, xa.z, xb.x, xb.z};
                const unsigned w23[4] = {xa.y, xa.w, xb.y, xb.w};
                #pragma unroll
                for (int j = 0; j < 4; ++j) {
                    const float x0 = __uint_as_float(w01[j] << 16);
                    const float x1 = __uint_as_float(w01[j] & 0xffff0000u);
                    const float x2 = __uint_as_float(w23[j] << 16);
                    const float x3 = __uint_as_float(w23[j] & 0xffff0000u);
                    macc[et][0 * 4 + j] = fmaf(x0, acc[j], macc[et][0 * 4 + j]);
                    macc[et][1 * 4 + j] = fmaf(x1, acc[j], macc[et][1 * 4 + j]);
                    macc[et][2 * 4 + j] = fmaf(x2, acc[j], macc[et][2 * 4 + j]);
                    macc[et][3 * 4 + j] = fmaf(x3, acc[j], macc[et][3 * 4 + j]);
                }
            }
        }

        // ---- scatter: 16 cl lanes = 16 channels contiguous (coalesced) ----
        #pragma unroll
        for (int et = 0; et < 2; ++et)
            #pragma unroll
            for (int j = 0; j < 4; ++j) {
                const int d = __shfl(dstv, et * 16 + kg * 4 + j);
                float* p = agg + (size_t)d * (B_ * CO) + cl;
                #pragma unroll
                for (int b = 0; b < 4; ++b)
                    atomicAdd(p + b * 16, macc[et][b * 4 + j]);
            }

        // ---- rotate prefetched metadata ----
        srcv = nsrc; dstv = ndst; au0 = na0; au1 = na1; au2 = na2;
    }
}

// out[b][n][o] = agg[n][b][o] / max(deg[n],1) + bias[o]
__global__ __launch_bounds__(256)
void finalize_kernel(const float* __restrict__ agg, const float* __restrict__ deg,
                     const float* __restrict__ bias, float* __restrict__ out)
{
    const int idx = blockIdx.x * 256 + threadIdx.x;
    if (idx >= B_ * NOUT_ * CO) return;
    const int o = idx & 15;
    const int n = (idx >> 4) % NOUT_;
    const int b = idx / (NOUT_ * CO);
    const float d = fmaxf(deg[n], 1.0f);
    out[idx] = agg[(size_t)n * (B_ * CO) + b * CO + o] / d + bias[o];
}

extern "C" void kernel_launch(void* const* d_in, const int* in_sizes, int n_in,
                              void* d_out, int out_size, void* d_ws, size_t ws_size,
                              hipStream_t stream)
{
    const float* x    = (const float*)d_in[0];
    const float* ipos = (const float*)d_in[1];
    const float* opos = (const float*)d_in[2];
    const int*   esrc = (const int*)d_in[3];
    const int*   edst = (const int*)d_in[4];
    const float* w1   = (const float*)d_in[5];
    const float* b1   = (const float*)d_in[6];
    const float* w2   = (const float*)d_in[7];
    const float* b2   = (const float*)d_in[8];
    const float* w3   = (const float*)d_in[9];
    const float* b3   = (const float*)d_in[10];
    const float* w4   = (const float*)d_in[11];
    const float* b4   = (const float*)d_in[12];
    const float* bias = (const float*)d_in[14];

    // Weight scratch in d_out's head (~139 KB); finalize overwrites it.
    char* ob = (char*)d_out;
    unsigned short* wcat = (unsigned short*)ob;              // 131072 B LDS image
    unsigned short* W1T  = (unsigned short*)(ob + 131072);   // 8192 B
    float* b1p = (float*)(ob + 139264);
    float* b2p = (float*)(ob + 139776);
    float* b3p = (float*)(ob + 140288);
    float* b4p = (float*)(ob + 140800);                      // ends 141824 B

    float* agg = (float*)d_ws;
    float* deg = agg + (size_t)NOUT_ * (B_ * CO);

    hipMemsetAsync(d_ws, 0,
                   ((size_t)NOUT_ * (B_ * CO) + NOUT_) * sizeof(float), stream);

    prep_kernel<<<275, 256, 0, stream>>>(w1, w2, w3, w4, b1, b2, b3, b4,
                                         wcat, W1T, b1p, b2p, b3p, b4p);

    hipFuncSetAttribute(reinterpret_cast<const void*>(edge_kernel),
                        hipFuncAttributeMaxDynamicSharedMemorySize,
                        (int)LDS_BYTES);
    edge_kernel<<<NBLK, 512, LDS_BYTES, stream>>>(
        x, ipos, opos, esrc, edst, wcat, W1T, b1p, b2p, b3p, b4p, agg, deg);

    const int total = B_ * NOUT_ * CO;
    finalize_kernel<<<(total + 255) / 256, 256, 0, stream>>>(agg, deg, bias,
                                                             (float*)d_out);
}